// Round 1
// baseline (351.485 us; speedup 1.0000x reference)
//
#include <hip/hip_runtime.h>

// Spectral self-attention with MODES=2 collapses to a rank-7 basis:
//   phi = {1, ch, sh, cw, sw, ch*cw - sh*sw, sh*cw + ch*sw},  theta = 2*pi/32
// Gram(phi) = diag(1024, 512,512,512,512,512,512) -> attention is a 56-dim dot.
// Pipeline: project(134MB read) -> qkv mode-mix -> cpb bias -> attention (64x64
// per (b,head)) -> out mode-mix -> materialize (134MB write).

namespace {

constexpr int Bn = 8, Sn = 64, Cn = 64, NHn = 8;
constexpr int ROWS = Bn * Sn;          // 512
constexpr int PLANES = ROWS * Cn;      // 32768
constexpr float PI2_32 = 0.19634954084936207f;  // 2*pi/32

// sqrt of per-mode score weights: scale = (1/1024)/sqrt(8);
// w0 = 1024*scale, wm = 512*scale; folded into BOTH q and k coefficients.
constexpr float SM0 = 0.59460355750136053f;   // (1/sqrt(8))^(1/2)
constexpr float SM1 = 0.42044820762685725f;   // (1/(2*sqrt(8)))^(1/2)

// workspace offsets (floats)
constexpr size_t OFF_A    = 0;                                  // [512][64][8]
constexpr size_t OFF_G    = OFF_A    + (size_t)ROWS * Cn * 8;   // [512][192][8]
constexpr size_t OFF_BIAS = OFF_G    + (size_t)ROWS * 192 * 8;  // [8][64][64]
constexpr size_t OFF_OG   = OFF_BIAS + (size_t)NHn * Sn * Sn;   // [512][64][8]
constexpr size_t OFF_FC   = OFF_OG   + (size_t)ROWS * Cn * 8;   // [512][64][8]
// total = 1,605,632 floats = ~6.2 MB of d_ws

// ---- Kernel 1: project each (b,s,c) 32x32 plane onto the 7 basis fns ----
__global__ __launch_bounds__(256) void k_project(const float* __restrict__ seq,
                                                 float* __restrict__ A) {
    __shared__ float2 tab[32];
    __shared__ float part[4][7];
    int tid = threadIdx.x;
    if (tid < 32) {
        float th = PI2_32 * (float)tid;
        tab[tid] = make_float2(cosf(th), sinf(th));
    }
    __syncthreads();
    size_t plane = blockIdx.x;
    float4 x = ((const float4*)(seq + plane * 1024))[tid];
    int p0 = tid << 2;
    int h = p0 >> 5, w0 = p0 & 31;
    float ch = tab[h].x, sh = tab[h].y;
    float xv[4] = {x.x, x.y, x.z, x.w};
    float s0 = 0.f, s3 = 0.f, s4 = 0.f;
#pragma unroll
    for (int k = 0; k < 4; ++k) {
        float cw = tab[w0 + k].x, sw = tab[w0 + k].y;
        s0 += xv[k];
        s3 = fmaf(xv[k], cw, s3);
        s4 = fmaf(xv[k], sw, s4);
    }
    // reduce row partials across the 8 lanes sharing this h (lanes tid>>3 equal)
#pragma unroll
    for (int off = 1; off <= 4; off <<= 1) {
        s0 += __shfl_xor(s0, off, 64);
        s3 += __shfl_xor(s3, off, 64);
        s4 += __shfl_xor(s4, off, 64);
    }
    float acc[7];
    acc[0] = s0;
    acc[1] = ch * s0;          // sum x*ch
    acc[2] = sh * s0;          // sum x*sh
    acc[3] = s3;               // sum x*cw
    acc[4] = s4;               // sum x*sw
    acc[5] = ch * s3 - sh * s4;  // sum x*(ch*cw - sh*sw)
    acc[6] = sh * s3 + ch * s4;  // sum x*(sh*cw + ch*sw)
#pragma unroll
    for (int off = 8; off <= 32; off <<= 1) {
#pragma unroll
        for (int m = 0; m < 7; ++m) acc[m] += __shfl_xor(acc[m], off, 64);
    }
    int wv = tid >> 6, ln = tid & 63;
    if (ln == 0) {
#pragma unroll
        for (int m = 0; m < 7; ++m) part[wv][m] = acc[m];
    }
    __syncthreads();
    if (tid < 7)
        A[plane * 8 + tid] = part[0][tid] + part[1][tid] + part[2][tid] + part[3][tid];
}

// ---- Mode mixing: complex per-mode C-contraction + irfft coefficient fold ----
// In:  [rows][64][8] 7-coeff vectors (a0..a6), weights wr/wi [64][O][4]
// Out: [rows][O][8] 7-coeff vectors.
// mode map in weights: .x=(0,0) .y=(0,1) .z=(1,0) .w=(1,1)
template <int O, int R>
__global__ void k_modemix(const float* __restrict__ In, const float* __restrict__ wr,
                          const float* __restrict__ wi, float* __restrict__ Out,
                          float fac0, float fac1, float fac2, float fac3,
                          int qk_scale) {
    __shared__ float As[R][64][8];
    int tid = threadIdx.x;
    int row0 = blockIdx.x * R;
    {
        const float4* src = (const float4*)(In + (size_t)row0 * 512);
        float4* dst = (float4*)&As[0][0][0];
        for (int idx = tid; idx < R * 128; idx += O) dst[idx] = src[idx];
    }
    __syncthreads();
    float acc[R][7];
#pragma unroll
    for (int r = 0; r < R; ++r)
#pragma unroll
        for (int m = 0; m < 7; ++m) acc[r][m] = 0.f;
    int o = tid;
    const float4* wr4p = (const float4*)wr;
    const float4* wi4p = (const float4*)wi;
    for (int c = 0; c < 64; ++c) {
        float4 r4 = wr4p[c * O + o];
        float4 i4 = wi4p[c * O + o];
#pragma unroll
        for (int r = 0; r < R; ++r) {
            const float* a = As[r][c];
            float a0 = a[0], a1 = a[1], a2 = a[2], a3 = a[3], a4 = a[4], a5 = a[5], a6 = a[6];
            acc[r][0] = fmaf(a0, r4.x, acc[r][0]);
            acc[r][1] = fmaf(a1, r4.z, fmaf(a2, i4.z, acc[r][1]));  //  Y10r
            acc[r][2] = fmaf(a2, r4.z, fmaf(-a1, i4.z, acc[r][2])); // -Y10i
            acc[r][3] = fmaf(a3, r4.y, fmaf(a4, i4.y, acc[r][3]));  //  Y01r
            acc[r][4] = fmaf(a4, r4.y, fmaf(-a3, i4.y, acc[r][4])); // -Y01i
            acc[r][5] = fmaf(a5, r4.w, fmaf(a6, i4.w, acc[r][5]));  //  Y11r
            acc[r][6] = fmaf(a6, r4.w, fmaf(-a5, i4.w, acc[r][6])); // -Y11i
        }
    }
    float f[7] = {fac0, fac1, fac1, fac2, fac2, fac3, fac3};
    bool scale_me = (qk_scale != 0) && (o < 128);  // q and k channels only
#pragma unroll
    for (int r = 0; r < R; ++r) {
#pragma unroll
        for (int m = 0; m < 7; ++m) {
            float v = acc[r][m] * f[m];
            if (scale_me) v *= (m == 0 ? SM0 : SM1);
            Out[(((size_t)(row0 + r)) * O + o) * 8 + m] = v;
        }
    }
}

// ---- CPB bias MLP: [8 heads][64][64] ----
__global__ __launch_bounds__(256) void k_cpb(const float* __restrict__ w1,
                                             const float* __restrict__ b1,
                                             const float* __restrict__ w2,
                                             float* __restrict__ bias) {
    __shared__ float W1[128], B1[64], W2[512];
    int tid = threadIdx.x;
    if (tid < 128) W1[tid] = w1[tid];
    if (tid < 64) B1[tid] = b1[tid];
    for (int idx = tid; idx < 512; idx += 256) W2[idx] = w2[idx];
    __syncthreads();
    int p = blockIdx.x * 256 + tid;  // p = i*64 + j
    int i = p >> 6, j = p & 63;
    float dx = (float)((i >> 3) - (j >> 3));
    float dy = (float)((i & 7) - (j & 7));
    float r0 = copysignf(log2f(1.f + fabsf(dx)), dx);
    float r1 = copysignf(log2f(1.f + fabsf(dy)), dy);
    float out[8] = {0.f, 0.f, 0.f, 0.f, 0.f, 0.f, 0.f, 0.f};
    for (int e = 0; e < 64; ++e) {
        float hv = fmaxf(fmaf(r0, W1[e], fmaf(r1, W1[64 + e], B1[e])), 0.f);
#pragma unroll
        for (int t = 0; t < 8; ++t) out[t] = fmaf(hv, W2[e * 8 + t], out[t]);
    }
#pragma unroll
    for (int t = 0; t < 8; ++t) bias[(t << 12) + p] = out[t];
}

// ---- Attention per (b,head): 64x56 q/k/v coefficient tiles ----
__global__ __launch_bounds__(256) void k_attn(const float* __restrict__ G,
                                              const float* __restrict__ bias,
                                              float* __restrict__ Og) {
    __shared__ float Qt[56][64];   // [dm][i]
    __shared__ float Kt[56][64];   // [dm][j]
    __shared__ float Vs[64][60];   // [j][dm] (padded)
    __shared__ float St[64][68];   // [j][i] raw scores -> unnormalized exp (padded)
    __shared__ float rsum[64];
    int tid = threadIdx.x;
    int bh = blockIdx.x, b = bh >> 3, h = bh & 7;

    // load q,k transposed; v direct. G: [row][192][8], channel = t*64 + h*8 + d
    for (int idx = tid; idx < 3584; idx += 256) {
        int dm = idx >> 6, s = idx & 63;
        int d = dm / 7, m = dm - d * 7;
        size_t base = ((size_t)(b * 64 + s)) * 1536;
        Qt[dm][s] = G[base + (size_t)(h * 8 + d) * 8 + m];
        Kt[dm][s] = G[base + (size_t)(64 + h * 8 + d) * 8 + m];
    }
    for (int idx = tid; idx < 4096; idx += 256) {
        int s = idx >> 6, dm = idx & 63;
        if (dm < 56) {
            int d = dm / 7, m = dm - d * 7;
            Vs[s][dm] = G[((size_t)(b * 64 + s)) * 1536 + (size_t)(128 + h * 8 + d) * 8 + m];
        }
    }
    __syncthreads();

    // scores: each thread computes a 4x4 tile of the 64x64 score matrix
    {
        int ti = tid >> 4, tj = tid & 15;
        int i0 = ti * 4, j0 = tj * 4;
        float acc[4][4] = {};
        for (int dm = 0; dm < 56; ++dm) {
            float4 q4 = *(const float4*)&Qt[dm][i0];
            float4 k4 = *(const float4*)&Kt[dm][j0];
            float qv[4] = {q4.x, q4.y, q4.z, q4.w};
            float kv[4] = {k4.x, k4.y, k4.z, k4.w};
#pragma unroll
            for (int ii = 0; ii < 4; ++ii)
#pragma unroll
                for (int jj = 0; jj < 4; ++jj) acc[ii][jj] = fmaf(qv[ii], kv[jj], acc[ii][jj]);
        }
        const float* bp = bias + (h << 12);
#pragma unroll
        for (int jj = 0; jj < 4; ++jj)
#pragma unroll
            for (int ii = 0; ii < 4; ++ii)
                St[j0 + jj][i0 + ii] = acc[ii][jj] + bp[(i0 + ii) * 64 + (j0 + jj)];
    }
    __syncthreads();

    // softmax over j for each row i; keep unnormalized exp in St + 1/sum
    {
        int i = tid >> 2, part = tid & 3;
        float mx = -1e30f;
#pragma unroll
        for (int jj = 0; jj < 16; ++jj) mx = fmaxf(mx, St[part * 16 + jj][i]);
        mx = fmaxf(mx, __shfl_xor(mx, 1, 64));
        mx = fmaxf(mx, __shfl_xor(mx, 2, 64));
        float sum = 0.f;
#pragma unroll
        for (int jj = 0; jj < 16; ++jj) {
            int j = part * 16 + jj;
            float e = expf(St[j][i] - mx);
            St[j][i] = e;
            sum += e;
        }
        sum += __shfl_xor(sum, 1, 64);
        sum += __shfl_xor(sum, 2, 64);
        if (part == 0) rsum[i] = 1.f / sum;
    }
    __syncthreads();

    // out: Og[i][dm] = (sum_j e[i,j] * V[j,dm]) / sum_i
    {
        int gi = tid >> 4, gd = tid & 15;
        if (gd < 14) {
            int i0 = gi * 4, dm0 = gd * 4;
            float acc[4][4] = {};
            for (int j = 0; j < 64; ++j) {
                float4 a4 = *(const float4*)&St[j][i0];
                float4 v4 = *(const float4*)&Vs[j][dm0];
                float av[4] = {a4.x, a4.y, a4.z, a4.w};
                float vv[4] = {v4.x, v4.y, v4.z, v4.w};
#pragma unroll
                for (int ii = 0; ii < 4; ++ii)
#pragma unroll
                    for (int k = 0; k < 4; ++k) acc[ii][k] = fmaf(av[ii], vv[k], acc[ii][k]);
            }
#pragma unroll
            for (int ii = 0; ii < 4; ++ii) {
                float ri = rsum[i0 + ii];
#pragma unroll
                for (int k = 0; k < 4; ++k) {
                    int dm = dm0 + k, d = dm / 7, m = dm - d * 7;
                    Og[(((size_t)(b * 64 + i0 + ii)) * 64 + h * 8 + d) * 8 + m] = acc[ii][k] * ri;
                }
            }
        }
    }
}

// ---- Kernel 6: materialize output field from 7 coefficients per plane ----
__global__ __launch_bounds__(256) void k_materialize(const float* __restrict__ Fc,
                                                     float* __restrict__ out) {
    __shared__ float2 tab[32];
    int tid = threadIdx.x;
    if (tid < 32) {
        float th = PI2_32 * (float)tid;
        tab[tid] = make_float2(cosf(th), sinf(th));
    }
    __syncthreads();
    size_t plane = blockIdx.x;
    const float* f = Fc + plane * 8;
    float f0 = f[0], f1 = f[1], f2 = f[2], f3 = f[3], f4 = f[4], f5 = f[5], f6 = f[6];
    int p0 = tid << 2, h = p0 >> 5, w0 = p0 & 31;
    float ch = tab[h].x, sh = tab[h].y;
    // val = t0 + cw*t1 + sw*t2  (cc/ss folded into h-dependent terms)
    float t0 = fmaf(f1, ch, fmaf(f2, sh, f0));
    float t1 = fmaf(f5, ch, fmaf(f6, sh, f3));
    float t2 = fmaf(-f5, sh, fmaf(f6, ch, f4));
    float4 o;
    o.x = fmaf(tab[w0 + 0].x, t1, fmaf(tab[w0 + 0].y, t2, t0));
    o.y = fmaf(tab[w0 + 1].x, t1, fmaf(tab[w0 + 1].y, t2, t0));
    o.z = fmaf(tab[w0 + 2].x, t1, fmaf(tab[w0 + 2].y, t2, t0));
    o.w = fmaf(tab[w0 + 3].x, t1, fmaf(tab[w0 + 3].y, t2, t0));
    ((float4*)(out + plane * 1024))[tid] = o;
}

}  // namespace

extern "C" void kernel_launch(void* const* d_in, const int* in_sizes, int n_in,
                              void* d_out, int out_size, void* d_ws, size_t ws_size,
                              hipStream_t stream) {
    const float* seq     = (const float*)d_in[0];
    const float* w_qkv_r = (const float*)d_in[1];
    const float* w_qkv_i = (const float*)d_in[2];
    const float* w_out_r = (const float*)d_in[3];
    const float* w_out_i = (const float*)d_in[4];
    const float* cpb_w1  = (const float*)d_in[5];
    const float* cpb_b1  = (const float*)d_in[6];
    const float* cpb_w2  = (const float*)d_in[7];
    // d_in[8], d_in[9]: n_sub_x = n_sub_y = 8 (fixed by S=64)

    float* ws   = (float*)d_ws;
    float* A    = ws + OFF_A;
    float* G    = ws + OFF_G;
    float* bias = ws + OFF_BIAS;
    float* Og   = ws + OFF_OG;
    float* Fc   = ws + OFF_FC;
    float* out  = (float*)d_out;

    k_project<<<dim3(PLANES), dim3(256), 0, stream>>>(seq, A);

    // qkv mix: g = (1/1024)*[Y00r, Y10r, -Y10i, 2*Y01r, -2*Y01i, 2*Y11r, -2*Y11i]
    k_modemix<192, 4><<<dim3(ROWS / 4), dim3(192), 0, stream>>>(
        A, w_qkv_r, w_qkv_i, G,
        1.f / 1024.f, 1.f / 1024.f, 2.f / 1024.f, 2.f / 1024.f, 1);

    k_cpb<<<dim3(16), dim3(256), 0, stream>>>(cpb_w1, cpb_b1, cpb_w2, bias);

    k_attn<<<dim3(Bn * NHn), dim3(256), 0, stream>>>(G, bias, Og);

    // out mix: forward modes of rank-7 field are diag(1024, 512*) -> combined
    // with (1/1024)*{1,1,2,2} gives factors {1, 0.5, 1, 1}
    k_modemix<64, 4><<<dim3(ROWS / 4), dim3(64), 0, stream>>>(
        Og, w_out_r, w_out_i, Fc, 1.f, 0.5f, 1.f, 1.f, 0);

    k_materialize<<<dim3(PLANES), dim3(256), 0, stream>>>(Fc, out);
}

// Round 3
// 297.236 us; speedup vs baseline: 1.1825x; 1.1825x over previous
//
#include <hip/hip_runtime.h>

// Spectral self-attention with MODES=2 collapses to a rank-7 basis:
//   phi = {1, ch, sh, cw, sw, ch*cw - sh*sw, sh*cw + ch*sw},  theta = 2*pi/32
// Gram(phi) = diag(1024, 512,...) -> attention is a 56-dim dot product.
// Pipeline: project(536MB read) -> qkv mode-mix -> cpb bias -> attention
// (64x64 per (b,head)) -> out mode-mix -> materialize (536MB write).
// R1/R2: 4 planes/block in the two streaming kernels, component-per-lane
// reduction (12 shuffles/plane vs 30), nontemporal loads/stores on the
// 536MB streams (via ext_vector_type — HIP float4 is rejected by the
// builtin), fuller grids on the mixes.

namespace {

typedef float vf4 __attribute__((ext_vector_type(4)));  // nontemporal-compatible

constexpr int Bn = 8, Sn = 64, Cn = 64, NHn = 8;
constexpr int ROWS = Bn * Sn;          // 512
constexpr int PLANES = ROWS * Cn;      // 32768
constexpr int NPP = 4;                 // planes per block in streaming kernels
constexpr float PI2_32 = 0.19634954084936207f;  // 2*pi/32

// sqrt of per-mode score weights: scale = (1/1024)/sqrt(8);
// w0 = 1024*scale, wm = 512*scale; folded into BOTH q and k coefficients.
constexpr float SM0 = 0.59460355750136053f;   // (1/sqrt(8))^(1/2)
constexpr float SM1 = 0.42044820762685725f;   // (1/(2*sqrt(8)))^(1/2)

// workspace offsets (floats)
constexpr size_t OFF_A    = 0;                                  // [512][64][8]
constexpr size_t OFF_G    = OFF_A    + (size_t)ROWS * Cn * 8;   // [512][192][8]
constexpr size_t OFF_BIAS = OFF_G    + (size_t)ROWS * 192 * 8;  // [8][64][64]
constexpr size_t OFF_OG   = OFF_BIAS + (size_t)NHn * Sn * Sn;   // [512][64][8]
constexpr size_t OFF_FC   = OFF_OG   + (size_t)ROWS * Cn * 8;   // [512][64][8]

// ---- Kernel 1: project 4 planes/block onto the 7 basis fns ----
__global__ __launch_bounds__(256) void k_project(const float* __restrict__ seq,
                                                 float* __restrict__ A) {
    __shared__ float part[NPP][4][8];  // [plane][wave][component]
    int tid = threadIdx.x;
    size_t plane0 = (size_t)blockIdx.x * NPP;
    const vf4* base = (const vf4*)(seq + plane0 * 1024);
    // 4 independent 16B loads -> 4 KB in flight per wave
    vf4 x0 = __builtin_nontemporal_load(base + tid);
    vf4 x1 = __builtin_nontemporal_load(base + 256 + tid);
    vf4 x2 = __builtin_nontemporal_load(base + 512 + tid);
    vf4 x3 = __builtin_nontemporal_load(base + 768 + tid);

    int h = tid >> 3;             // row within plane (0..31)
    int w0 = (tid << 2) & 31;     // column of first element
    float ch = cosf(PI2_32 * (float)h), sh = sinf(PI2_32 * (float)h);
    float cw[4], sw[4];
#pragma unroll
    for (int k = 0; k < 4; ++k) {
        float a = PI2_32 * (float)(w0 + k);
        cw[k] = cosf(a);
        sw[k] = sinf(a);
    }
    // component owned by this lane (0..6 used); basis weights on (s0,s3,s4)
    int c = tid & 7;
    float wc0 = (c == 0) ? 1.f : (c == 1) ? ch : (c == 2) ? sh : 0.f;
    float wc3 = (c == 3) ? 1.f : (c == 5) ? ch : (c == 6) ? sh : 0.f;
    float wc4 = (c == 4) ? 1.f : (c == 5) ? -sh : (c == 6) ? ch : 0.f;

    vf4 xs[NPP] = {x0, x1, x2, x3};
#pragma unroll
    for (int p = 0; p < NPP; ++p) {
        float xv[4] = {xs[p].x, xs[p].y, xs[p].z, xs[p].w};
        float s0 = 0.f, s3 = 0.f, s4 = 0.f;
#pragma unroll
        for (int k = 0; k < 4; ++k) {
            s0 += xv[k];
            s3 = fmaf(xv[k], cw[k], s3);
            s4 = fmaf(xv[k], sw[k], s4);
        }
        // reduce across the 8 lanes sharing this row h
#pragma unroll
        for (int off = 1; off <= 4; off <<= 1) {
            s0 += __shfl_xor(s0, off, 64);
            s3 += __shfl_xor(s3, off, 64);
            s4 += __shfl_xor(s4, off, 64);
        }
        // each lane in the group of 8 computes ITS component
        float acc = fmaf(wc0, s0, fmaf(wc3, s3, wc4 * s4));
        // reduce over the wave's 8 rows (same component)
#pragma unroll
        for (int off = 8; off <= 32; off <<= 1) acc += __shfl_xor(acc, off, 64);
        if ((tid & 63) < 8) part[p][tid >> 6][c] = acc;
    }
    __syncthreads();
    if (tid < NPP * 8) {
        int p = tid >> 3, cc = tid & 7;
        if (cc < 7)
            A[(plane0 + p) * 8 + cc] =
                part[p][0][cc] + part[p][1][cc] + part[p][2][cc] + part[p][3][cc];
    }
}

// ---- Mode mixing: complex per-mode C-contraction + irfft coefficient fold ----
// In:  [rows][64][8] 7-coeff vectors (a0..a6), weights wr/wi [64][O][4]
// Out: [rows][O][8] 7-coeff vectors.
// mode map in weights: .x=(0,0) .y=(0,1) .z=(1,0) .w=(1,1)
template <int O, int R>
__global__ void k_modemix(const float* __restrict__ In, const float* __restrict__ wr,
                          const float* __restrict__ wi, float* __restrict__ Out,
                          float fac0, float fac1, float fac2, float fac3,
                          int qk_scale) {
    __shared__ float As[R][64][8];
    int tid = threadIdx.x;
    int row0 = blockIdx.x * R;
    {
        const float4* src = (const float4*)(In + (size_t)row0 * 512);
        float4* dst = (float4*)&As[0][0][0];
        for (int idx = tid; idx < R * 128; idx += O) dst[idx] = src[idx];
    }
    __syncthreads();
    float acc[R][7];
#pragma unroll
    for (int r = 0; r < R; ++r)
#pragma unroll
        for (int m = 0; m < 7; ++m) acc[r][m] = 0.f;
    int o = tid;
    const float4* wr4p = (const float4*)wr;
    const float4* wi4p = (const float4*)wi;
    for (int c = 0; c < 64; ++c) {
        float4 r4 = wr4p[c * O + o];
        float4 i4 = wi4p[c * O + o];
#pragma unroll
        for (int r = 0; r < R; ++r) {
            const float* a = As[r][c];
            float a0 = a[0], a1 = a[1], a2 = a[2], a3 = a[3], a4 = a[4], a5 = a[5], a6 = a[6];
            acc[r][0] = fmaf(a0, r4.x, acc[r][0]);
            acc[r][1] = fmaf(a1, r4.z, fmaf(a2, i4.z, acc[r][1]));  //  Y10r
            acc[r][2] = fmaf(a2, r4.z, fmaf(-a1, i4.z, acc[r][2])); // -Y10i
            acc[r][3] = fmaf(a3, r4.y, fmaf(a4, i4.y, acc[r][3]));  //  Y01r
            acc[r][4] = fmaf(a4, r4.y, fmaf(-a3, i4.y, acc[r][4])); // -Y01i
            acc[r][5] = fmaf(a5, r4.w, fmaf(a6, i4.w, acc[r][5]));  //  Y11r
            acc[r][6] = fmaf(a6, r4.w, fmaf(-a5, i4.w, acc[r][6])); // -Y11i
        }
    }
    float f[7] = {fac0, fac1, fac1, fac2, fac2, fac3, fac3};
    bool scale_me = (qk_scale != 0) && (o < 128);  // q and k channels only
#pragma unroll
    for (int r = 0; r < R; ++r) {
#pragma unroll
        for (int m = 0; m < 7; ++m) {
            float v = acc[r][m] * f[m];
            if (scale_me) v *= (m == 0 ? SM0 : SM1);
            Out[(((size_t)(row0 + r)) * O + o) * 8 + m] = v;
        }
    }
}

// ---- CPB bias MLP: [8 heads][64][64] ----
__global__ __launch_bounds__(256) void k_cpb(const float* __restrict__ w1,
                                             const float* __restrict__ b1,
                                             const float* __restrict__ w2,
                                             float* __restrict__ bias) {
    __shared__ float W1[128], B1[64], W2[512];
    int tid = threadIdx.x;
    if (tid < 128) W1[tid] = w1[tid];
    if (tid < 64) B1[tid] = b1[tid];
    for (int idx = tid; idx < 512; idx += 256) W2[idx] = w2[idx];
    __syncthreads();
    int p = blockIdx.x * 256 + tid;  // p = i*64 + j
    int i = p >> 6, j = p & 63;
    float dx = (float)((i >> 3) - (j >> 3));
    float dy = (float)((i & 7) - (j & 7));
    float r0 = copysignf(log2f(1.f + fabsf(dx)), dx);
    float r1 = copysignf(log2f(1.f + fabsf(dy)), dy);
    float out[8] = {0.f, 0.f, 0.f, 0.f, 0.f, 0.f, 0.f, 0.f};
    for (int e = 0; e < 64; ++e) {
        float hv = fmaxf(fmaf(r0, W1[e], fmaf(r1, W1[64 + e], B1[e])), 0.f);
#pragma unroll
        for (int t = 0; t < 8; ++t) out[t] = fmaf(hv, W2[e * 8 + t], out[t]);
    }
#pragma unroll
    for (int t = 0; t < 8; ++t) bias[(t << 12) + p] = out[t];
}

// ---- Attention per (b,head): 64x56 q/k/v coefficient tiles ----
__global__ __launch_bounds__(256) void k_attn(const float* __restrict__ G,
                                              const float* __restrict__ bias,
                                              float* __restrict__ Og) {
    __shared__ float Qt[56][64];   // [dm][i]
    __shared__ float Kt[56][64];   // [dm][j]
    __shared__ float Vs[64][60];   // [j][dm] (padded)
    __shared__ float St[64][68];   // [j][i] raw scores -> unnormalized exp (padded)
    __shared__ float rsum[64];
    int tid = threadIdx.x;
    int bh = blockIdx.x, b = bh >> 3, h = bh & 7;

    // load q,k transposed; v direct. G: [row][192][8], channel = t*64 + h*8 + d
    for (int idx = tid; idx < 3584; idx += 256) {
        int dm = idx >> 6, s = idx & 63;
        int d = dm / 7, m = dm - d * 7;
        size_t base = ((size_t)(b * 64 + s)) * 1536;
        Qt[dm][s] = G[base + (size_t)(h * 8 + d) * 8 + m];
        Kt[dm][s] = G[base + (size_t)(64 + h * 8 + d) * 8 + m];
    }
    for (int idx = tid; idx < 4096; idx += 256) {
        int s = idx >> 6, dm = idx & 63;
        if (dm < 56) {
            int d = dm / 7, m = dm - d * 7;
            Vs[s][dm] = G[((size_t)(b * 64 + s)) * 1536 + (size_t)(128 + h * 8 + d) * 8 + m];
        }
    }
    __syncthreads();

    // scores: each thread computes a 4x4 tile of the 64x64 score matrix
    {
        int ti = tid >> 4, tj = tid & 15;
        int i0 = ti * 4, j0 = tj * 4;
        float acc[4][4] = {};
        for (int dm = 0; dm < 56; ++dm) {
            float4 q4 = *(const float4*)&Qt[dm][i0];
            float4 k4 = *(const float4*)&Kt[dm][j0];
            float qv[4] = {q4.x, q4.y, q4.z, q4.w};
            float kv[4] = {k4.x, k4.y, k4.z, k4.w};
#pragma unroll
            for (int ii = 0; ii < 4; ++ii)
#pragma unroll
                for (int jj = 0; jj < 4; ++jj) acc[ii][jj] = fmaf(qv[ii], kv[jj], acc[ii][jj]);
        }
        const float* bp = bias + (h << 12);
#pragma unroll
        for (int jj = 0; jj < 4; ++jj)
#pragma unroll
            for (int ii = 0; ii < 4; ++ii)
                St[j0 + jj][i0 + ii] = acc[ii][jj] + bp[(i0 + ii) * 64 + (j0 + jj)];
    }
    __syncthreads();

    // softmax over j for each row i; keep unnormalized exp in St + 1/sum
    {
        int i = tid >> 2, part = tid & 3;
        float mx = -1e30f;
#pragma unroll
        for (int jj = 0; jj < 16; ++jj) mx = fmaxf(mx, St[part * 16 + jj][i]);
        mx = fmaxf(mx, __shfl_xor(mx, 1, 64));
        mx = fmaxf(mx, __shfl_xor(mx, 2, 64));
        float sum = 0.f;
#pragma unroll
        for (int jj = 0; jj < 16; ++jj) {
            int j = part * 16 + jj;
            float e = expf(St[j][i] - mx);
            St[j][i] = e;
            sum += e;
        }
        sum += __shfl_xor(sum, 1, 64);
        sum += __shfl_xor(sum, 2, 64);
        if (part == 0) rsum[i] = 1.f / sum;
    }
    __syncthreads();

    // out: Og[i][dm] = (sum_j e[i,j] * V[j,dm]) / sum_i
    {
        int gi = tid >> 4, gd = tid & 15;
        if (gd < 14) {
            int i0 = gi * 4, dm0 = gd * 4;
            float acc[4][4] = {};
            for (int j = 0; j < 64; ++j) {
                float4 a4 = *(const float4*)&St[j][i0];
                float4 v4 = *(const float4*)&Vs[j][dm0];
                float av[4] = {a4.x, a4.y, a4.z, a4.w};
                float vv[4] = {v4.x, v4.y, v4.z, v4.w};
#pragma unroll
                for (int ii = 0; ii < 4; ++ii)
#pragma unroll
                    for (int k = 0; k < 4; ++k) acc[ii][k] = fmaf(av[ii], vv[k], acc[ii][k]);
            }
#pragma unroll
            for (int ii = 0; ii < 4; ++ii) {
                float ri = rsum[i0 + ii];
#pragma unroll
                for (int k = 0; k < 4; ++k) {
                    int dm = dm0 + k, d = dm / 7, m = dm - d * 7;
                    Og[(((size_t)(b * 64 + i0 + ii)) * 64 + h * 8 + d) * 8 + m] = acc[ii][k] * ri;
                }
            }
        }
    }
}

// ---- Kernel 6: materialize 4 planes/block from 7 coefficients each ----
__global__ __launch_bounds__(256) void k_materialize(const float* __restrict__ Fc,
                                                     float* __restrict__ out) {
    __shared__ float fs[NPP][8];
    int tid = threadIdx.x;
    size_t plane0 = (size_t)blockIdx.x * NPP;
    if (tid < NPP * 8) fs[tid >> 3][tid & 7] = Fc[plane0 * 8 + tid];
    int h = tid >> 3, w0 = (tid << 2) & 31;
    float ch = cosf(PI2_32 * (float)h), sh = sinf(PI2_32 * (float)h);
    float cw[4], sw[4];
#pragma unroll
    for (int k = 0; k < 4; ++k) {
        float a = PI2_32 * (float)(w0 + k);
        cw[k] = cosf(a);
        sw[k] = sinf(a);
    }
    __syncthreads();
    vf4* ob = (vf4*)(out + plane0 * 1024);
#pragma unroll
    for (int p = 0; p < NPP; ++p) {
        const float* f = fs[p];
        float t0 = fmaf(f[1], ch, fmaf(f[2], sh, f[0]));
        float t1 = fmaf(f[5], ch, fmaf(f[6], sh, f[3]));
        float t2 = fmaf(-f[5], sh, fmaf(f[6], ch, f[4]));
        vf4 o;
        o.x = fmaf(cw[0], t1, fmaf(sw[0], t2, t0));
        o.y = fmaf(cw[1], t1, fmaf(sw[1], t2, t0));
        o.z = fmaf(cw[2], t1, fmaf(sw[2], t2, t0));
        o.w = fmaf(cw[3], t1, fmaf(sw[3], t2, t0));
        __builtin_nontemporal_store(o, ob + p * 256 + tid);
    }
}

}  // namespace

extern "C" void kernel_launch(void* const* d_in, const int* in_sizes, int n_in,
                              void* d_out, int out_size, void* d_ws, size_t ws_size,
                              hipStream_t stream) {
    const float* seq     = (const float*)d_in[0];
    const float* w_qkv_r = (const float*)d_in[1];
    const float* w_qkv_i = (const float*)d_in[2];
    const float* w_out_r = (const float*)d_in[3];
    const float* w_out_i = (const float*)d_in[4];
    const float* cpb_w1  = (const float*)d_in[5];
    const float* cpb_b1  = (const float*)d_in[6];
    const float* cpb_w2  = (const float*)d_in[7];
    // d_in[8], d_in[9]: n_sub_x = n_sub_y = 8 (fixed by S=64)

    float* ws   = (float*)d_ws;
    float* A    = ws + OFF_A;
    float* G    = ws + OFF_G;
    float* bias = ws + OFF_BIAS;
    float* Og   = ws + OFF_OG;
    float* Fc   = ws + OFF_FC;
    float* out  = (float*)d_out;

    // cpb has no upstream deps — launch first so it's off the critical tail
    k_cpb<<<dim3(16), dim3(256), 0, stream>>>(cpb_w1, cpb_b1, cpb_w2, bias);

    k_project<<<dim3(PLANES / NPP), dim3(256), 0, stream>>>(seq, A);

    // qkv mix: g = (1/1024)*[Y00r, Y10r, -Y10i, 2*Y01r, -2*Y01i, 2*Y11r, -2*Y11i]
    k_modemix<192, 2><<<dim3(ROWS / 2), dim3(192), 0, stream>>>(
        A, w_qkv_r, w_qkv_i, G,
        1.f / 1024.f, 1.f / 1024.f, 2.f / 1024.f, 2.f / 1024.f, 1);

    k_attn<<<dim3(Bn * NHn), dim3(256), 0, stream>>>(G, bias, Og);

    // out mix: forward modes of rank-7 field are diag(1024, 512*) -> combined
    // with (1/1024)*{1,1,2,2} gives factors {1, 0.5, 1, 1}
    k_modemix<64, 1><<<dim3(ROWS), dim3(64), 0, stream>>>(
        Og, w_out_r, w_out_i, Fc, 1.f, 0.5f, 1.f, 1.f, 0);

    k_materialize<<<dim3(PLANES / NPP), dim3(256), 0, stream>>>(Fc, out);
}